// Round 14
// baseline (208.710 us; speedup 1.0000x reference)
//
#include <hip/hip_runtime.h>
#include <stdint.h>

#define NROWS 65536
#define HD 1024

typedef __attribute__((ext_vector_type(8))) short bf16x8;   // 8 bf16 in 4 VGPRs
typedef __attribute__((ext_vector_type(16))) float f32x16;  // MFMA 32x32 accumulator

typedef __attribute__((address_space(1))) const unsigned int* gas_ptr;
typedef __attribute__((address_space(3))) unsigned int* las_ptr;

__device__ __forceinline__ unsigned short f2bf(float f) {
  union { float f; uint32_t u; } v; v.f = f;
  uint32_t u = v.u;
  return (unsigned short)((u + 0x7fffu + ((u >> 16) & 1u)) >> 16);  // RNE
}

__device__ __forceinline__ void gl16(const void* g, void* l) {
  __builtin_amdgcn_global_load_lds((gas_ptr)g, (las_ptr)l, 16, 0, 0);
}

// ---------------- prep: W2 fp32 -> bf16 packed in MFMA-fragment order (R13) ----------------
// W2pk granule i (16B): lane=i&63, f=(i>>6)&15, T=(i>>10)&15, ct=i>>14;
// f = wn*8 + cb*4 + p*2 + kl. col = ct*128+wn*64+cb*32+(lane&31),
// k = T*64 + p*32 + kl*16 + (lane>>5)*8. A wave's frag load is 64x16B contiguous.
__global__ void k_w2pk(const float* __restrict__ W2, unsigned short* __restrict__ W2pk) {
  int i = blockIdx.x * 256 + threadIdx.x;   // 131072 granules
  int lane = i & 63, f = (i >> 6) & 15, T = (i >> 10) & 15, ct = i >> 14;
  int kl = f & 1, p = (f >> 1) & 1, cb = (f >> 2) & 1, wn = f >> 3;
  int col = ct * 128 + wn * 64 + cb * 32 + (lane & 31);
  int k = T * 64 + p * 32 + kl * 16 + (lane >> 5) * 8;
  const float4* s4 = (const float4*)(W2 + (size_t)col * HD + k);
  float4 a = s4[0], b = s4[1];
  uint4 pk;
  pk.x = (uint32_t)f2bf(a.x) | ((uint32_t)f2bf(a.y) << 16);
  pk.y = (uint32_t)f2bf(a.z) | ((uint32_t)f2bf(a.w) << 16);
  pk.z = (uint32_t)f2bf(b.x) | ((uint32_t)f2bf(b.y) << 16);
  pk.w = (uint32_t)f2bf(b.z) | ((uint32_t)f2bf(b.w) << 16);
  *(uint4*)(W2pk + (size_t)i * 8) = pk;
}

// ---------------- layer 1 (R13): h bf16 [65536][1024], granule swizzle (g&3)^((row>>1)&3) ----------------
__global__ __launch_bounds__(512) void k_layer1(
    const float* __restrict__ x, const float* __restrict__ W1,
    const float* __restrict__ b1, const float* __restrict__ Wmeta,
    const float* __restrict__ bmeta, unsigned short* __restrict__ h) {
  __shared__ float xs[64 * 12];
  int r0 = blockIdx.x * 64;
  int t = threadIdx.x;
  int j0 = t * 2;
  float w1a = W1[j0], w1b = W1[j0 + 1];
  float b1a = b1[j0], b1b = b1[j0 + 1];
  float wma[10], wmb[10], bma[10], bmb[10];
#pragma unroll
  for (int e = 0; e < 10; e++) {
    float2 wmv = *(const float2*)(Wmeta + e * HD + j0);
    float2 bmv = *(const float2*)(bmeta + e * HD + j0);
    wma[e] = wmv.x; wmb[e] = wmv.y; bma[e] = bmv.x; bmb[e] = bmv.y;
  }
  for (int i = t; i < 64 * 12; i += 512) xs[i] = x[(size_t)r0 * 12 + i];
  __syncthreads();
  int g = j0 >> 3;
  for (int r = 0; r < 64; r++) {
    const float* xr = xs + r * 12;
    float delta = xr[10], phi = xr[11];
    float s1a = 0.f, s1b = 0.f, s2a = 0.f, s2b = 0.f;
#pragma unroll
    for (int e = 0; e < 10; e++) {
      float oh = xr[e];
      s1a = fmaf(oh, wma[e], s1a);
      s1b = fmaf(oh, wmb[e], s1b);
      s2a = fmaf(oh, bma[e], s2a);
      s2b = fmaf(oh, bmb[e], s2b);
    }
    float pa = fmaf(delta, w1a, b1a) + fmaf(phi, s1a, s2a);
    float pb = fmaf(delta, w1b, b1b) + fmaf(phi, s1b, s2b);
    pa = fmaxf(pa, 0.f); pb = fmaxf(pb, 0.f);
    uint32_t pk = (uint32_t)f2bf(pa) | ((uint32_t)f2bf(pb) << 16);
    int rr = r0 + r;
    int gs = (g & 124) | ((g & 3) ^ ((rr >> 1) & 3));
    *(uint32_t*)(h + (size_t)rr * HD + gs * 8 + (j0 & 7)) = pk;
  }
}

// ---------------- layers 2+3: R13 frame + paired-tile staging (half the sync drains) ----------------
// grid 4096 (XCD-swizzled) = 512 rt x 8 ct; 256 threads = 4 waves (2x2), wave tile 64x64
// = 2x2 of 32x32x16 bf16 MFMA (acc 64 AGPR). LDS: A-only, 2 tiles/phase = 32 KB.
// Per phase (2 K-tiles = 128 k): {8 gl_lds (A(2t) panels @0/8192, A(2t+1) @16384/24576) |
//   __syncthreads | B(2t) 8 reg-frag loads (L2) + 8 ds_read + 16 MFMA |
//   B(2t+1) + 8 ds_read + 16 MFMA | __syncthreads}.
// 8 drain windows instead of 16; B(2t+1) L2 latency hides under MFMA(2t).
// launch_bounds(256,4) caps unified regs at 128 so compiler hoisting can't cut occupancy.
__global__ __launch_bounds__(256, 4) void k_gemm(
    const unsigned short* __restrict__ h, const unsigned short* __restrict__ W2pk,
    const float* __restrict__ b2, const float* __restrict__ W3,
    float* __restrict__ partial) {
  __shared__ char lds[34816];   // A: 4 panels @0/8192/16384/24576; epilogue reuses 33792 B
  int tid = threadIdx.x;
  // XCD swizzle: 4096 blocks = 8 XCDs x 512; XCD k gets contiguous logical range.
  int b = (int)blockIdx.x;
  int bx = ((b & 7) << 9) | (b >> 3);
  int rt = bx >> 3, ct = bx & 7;   // 8 consecutive bx share rt -> A-panel L2 reuse
  size_t r0 = (size_t)rt * 128;
  int c0 = ct * 128;
  int w = tid >> 6, lane = tid & 63;
  int wm = w >> 1, wn = w & 1;
  int l31 = lane & 31, hi = lane >> 5;
  int sw = (l31 >> 1) & 3;   // A granule swizzle key (row bases are multiples of 32)

  f32x16 acc[2][2];
#pragma unroll
  for (int rb = 0; rb < 2; rb++)
#pragma unroll
    for (int cb = 0; cb < 2; cb++)
#pragma unroll
      for (int i = 0; i < 16; i++) acc[rb][cb][i] = 0.f;

  int arow0 = (wm * 64 + 0  + l31) * 64;
  int arow1 = (wm * 64 + 32 + l31) * 64;
  // per-wave packed-B base for this ct: T-tile stride 16*512, frag (cb*4+p*2+kl)*512
  const unsigned short* bwave = W2pk + ((size_t)ct * 16 * 16 + (size_t)wn * 8) * 512 + lane * 8;

  for (int TT = 0; TT < 8; TT++) {
    int T0 = TT * 2;
    // stage A(T0) -> panels @0/8192, A(T0+1) -> @16384/24576 (8 gl_lds/thread)
#pragma unroll
    for (int q = 0; q < 2; q++) {
      int s = tid + 256 * q;            // 0..511
      int row = s >> 2, g4 = s & 3;
      const unsigned short* hsrc = h + (r0 + row) * (size_t)HD + T0 * 64 + g4 * 8;
      gl16(hsrc,      lds +         (size_t)s * 16);
      gl16(hsrc + 32, lds +  8192 + (size_t)s * 16);
      gl16(hsrc + 64, lds + 16384 + (size_t)s * 16);
      gl16(hsrc + 96, lds + 24576 + (size_t)s * 16);
    }
    __syncthreads();   // drains vmcnt: both tiles in LDS; prior reads done
#pragma unroll
    for (int half = 0; half < 2; half++) {
      // B fragments for K-tile T0+half straight to registers (coalesced, L2-resident)
      const unsigned short* bt = bwave + (size_t)(T0 + half) * 16 * 512;
      bf16x8 B00 = *(const bf16x8*)(bt + 0 * 512);
      bf16x8 B01 = *(const bf16x8*)(bt + 1 * 512);
      bf16x8 B02 = *(const bf16x8*)(bt + 2 * 512);
      bf16x8 B03 = *(const bf16x8*)(bt + 3 * 512);
      bf16x8 B10 = *(const bf16x8*)(bt + 4 * 512);
      bf16x8 B11 = *(const bf16x8*)(bt + 5 * 512);
      bf16x8 B12 = *(const bf16x8*)(bt + 6 * 512);
      bf16x8 B13 = *(const bf16x8*)(bt + 7 * 512);
#pragma unroll
      for (int p = 0; p < 2; p++) {
        const char* lA = lds + half * 16384 + p * 8192;
#pragma unroll
        for (int kl = 0; kl < 2; kl++) {
          int slot = ((kl * 2 + hi) ^ sw) << 4;
          bf16x8 a0 = *(const bf16x8*)(lA + arow0 + slot);
          bf16x8 a1 = *(const bf16x8*)(lA + arow1 + slot);
          bf16x8 bb0 = (p == 0) ? (kl == 0 ? B00 : B01) : (kl == 0 ? B02 : B03);
          bf16x8 bb1 = (p == 0) ? (kl == 0 ? B10 : B11) : (kl == 0 ? B12 : B13);
          acc[0][0] = __builtin_amdgcn_mfma_f32_32x32x16_bf16(a0, bb0, acc[0][0], 0, 0, 0);
          acc[0][1] = __builtin_amdgcn_mfma_f32_32x32x16_bf16(a0, bb1, acc[0][1], 0, 0, 0);
          acc[1][0] = __builtin_amdgcn_mfma_f32_32x32x16_bf16(a1, bb0, acc[1][0], 0, 0, 0);
          acc[1][1] = __builtin_amdgcn_mfma_f32_32x32x16_bf16(a1, bb1, acc[1][1], 0, 0, 0);
        }
      }
    }
    __syncthreads();
  }

  // ---- epilogue (R5 verbatim): v = relu(acc+b2); o = v x W3^T; LDS transpose-reduce ----
  float b2c[2], w30[2], w31[2];
#pragma unroll
  for (int cb = 0; cb < 2; cb++) {
    int c = c0 + wn * 64 + cb * 32 + l31;
    b2c[cb] = b2[c];
    w30[cb] = W3[c];
    w31[cb] = W3[HD + c];
  }
  // padded layout: line = (wm*32+rowf)*2 + wn in [0,128); float2 slot = line*33 + l31
  float2* sE = (float2*)lds;
#pragma unroll
  for (int rb = 0; rb < 2; rb++) {
    __syncthreads();
#pragma unroll
    for (int reg = 0; reg < 16; reg++) {
      float v0 = fmaxf(acc[rb][0][reg] + b2c[0], 0.f);
      float v1 = fmaxf(acc[rb][1][reg] + b2c[1], 0.f);
      float2 o;
      o.x = v0 * w30[0] + v1 * w30[1];
      o.y = v0 * w31[0] + v1 * w31[1];
      int rowf = (reg & 3) + 8 * (reg >> 2) + 4 * hi;   // verified C/D row map
      int line = (wm * 32 + rowf) * 2 + wn;
      sE[line * 33 + l31] = o;
    }
    __syncthreads();
    // reduce: 128 targets (bi 2 x rowf 32 x d 2), 2 threads each (half = wn index)
    int half = tid & 1, tgt = tid >> 1;
    int d = tgt & 1, rowf_t = (tgt >> 1) & 31, bi = tgt >> 6;
    int line0 = (bi * 32 + rowf_t) * 2 + half;
    const float* sf = (const float*)lds;
    float s = 0.f;
#pragma unroll
    for (int j = 0; j < 32; j++) s += sf[(line0 * 33 + j) * 2 + d];
    s += __shfl_xor(s, 1);
    if (half == 0) {
      int row = bi * 64 + rb * 32 + rowf_t;
      partial[(size_t)ct * (NROWS * 2) + (r0 + row) * 2 + d] = s;
    }
  }
}

// ---------------- final: out = b3 + sum over 8 col-tile partials ----------------
__global__ void k_reduce(const float* __restrict__ partial, const float* __restrict__ b3,
                         float* __restrict__ out) {
  int i = blockIdx.x * 256 + threadIdx.x;  // 131072
  float s = b3[i & 1];
#pragma unroll
  for (int ctt = 0; ctt < 8; ctt++) s += partial[(size_t)ctt * 131072 + i];
  out[i] = s;
}

extern "C" void kernel_launch(void* const* d_in, const int* in_sizes, int n_in,
                              void* d_out, int out_size, void* d_ws, size_t ws_size,
                              hipStream_t stream) {
  const float* x     = (const float*)d_in[0];
  const float* W1    = (const float*)d_in[1];
  const float* b1    = (const float*)d_in[2];
  const float* Wmeta = (const float*)d_in[3];
  const float* bmeta = (const float*)d_in[4];
  const float* W2    = (const float*)d_in[5];
  const float* b2    = (const float*)d_in[6];
  const float* W3    = (const float*)d_in[7];
  const float* b3    = (const float*)d_in[8];
  float* out = (float*)d_out;

  char* ws = (char*)d_ws;
  unsigned short* hbuf  = (unsigned short*)ws;                              // 128 MiB
  unsigned short* W2pk  = (unsigned short*)(ws + (size_t)NROWS * HD * 2);   // 2 MiB
  float* partial = (float*)(ws + (size_t)NROWS * HD * 2 + (size_t)HD * HD * 2);  // 4 MiB (8 slices)

  k_w2pk<<<512, 256, 0, stream>>>(W2, W2pk);
  k_layer1<<<1024, 512, 0, stream>>>(x, W1, b1, Wmeta, bmeta, hbuf);
  k_gemm<<<4096, 256, 0, stream>>>(hbuf, W2pk, b2, W3, partial);
  k_reduce<<<512, 256, 0, stream>>>(partial, b3, out);
}